// Round 7
// baseline (174.642 us; speedup 1.0000x reference)
//
#include <hip/hip_runtime.h>

#define IN_CH 128
#define OUT_CH 10
#define YPAD 16                    // y row padded to 64 B (one cache line)
#define SHIFT 7                    // nodes per bucket = 128
#define NPB 128
#define CHUNK 4096                 // edges per block in binning kernels
#define CCAP 1024                  // pairs per counting-sort round in k_accum

// ============================================================================
// Shared helpers
// ============================================================================

// Detect whether edge_index arrived as int64 or int32 (odd words all zero
// for int64 values < 2^17). flag=1 -> int32, flag=0 -> int64. Deterministic.
__global__ void k_detect(const unsigned int* __restrict__ w, int* flag,
                         int nwords_check) {
    __shared__ int any_nz;
    if (threadIdx.x == 0) any_nz = 0;
    __syncthreads();
    int local = 0;
    for (int i = threadIdx.x; i < nwords_check; i += blockDim.x)
        if (w[2 * i + 1] != 0u) local = 1;
    if (local) atomicOr(&any_nz, 1);
    __syncthreads();
    if (threadIdx.x == 0) *flag = any_nz;
}

__global__ void k_zero_i(int* __restrict__ p, int n) {
    int i = blockIdx.x * blockDim.x + threadIdx.x;
    int stride = gridDim.x * blockDim.x;
    for (; i < n; i += stride) p[i] = 0;
}

__device__ __forceinline__ int load_dst(const void* ei, bool is32, long long E,
                                        long long i) {
    return is32 ? ((const int*)ei)[E + i] : (int)((const long long*)ei)[E + i];
}
__device__ __forceinline__ int load_src(const void* ei, bool is32, long long E,
                                        long long i) {
    return is32 ? ((const int*)ei)[i] : (int)((const long long*)ei)[i];
}

// ============================================================================
// Bucketed-gather path (primary)
// ============================================================================

// Per-chunk LDS histogram of buckets, flushed with one atomic per bucket.
__global__ void k_bincount(const void* __restrict__ ei,
                           const int* __restrict__ flag, int E,
                           int* __restrict__ bcnt, int NB) {
    __shared__ int h[1024];
    for (int i = threadIdx.x; i < NB; i += blockDim.x) h[i] = 0;
    __syncthreads();
    const bool is32 = (*flag != 0);
    long long base = (long long)blockIdx.x * CHUNK;
    int lim = (int)min((long long)CHUNK, (long long)E - base);
    for (int i = threadIdx.x; i < lim; i += blockDim.x) {
        int d = load_dst(ei, is32, E, base + i);
        atomicAdd(&h[d >> SHIFT], 1);
    }
    __syncthreads();
    for (int i = threadIdx.x; i < NB; i += blockDim.x)
        if (h[i]) atomicAdd(&bcnt[i], h[i]);
}

// Exclusive scan of bcnt[NB] (NB <= 1024) -> bbase, gcursor
__global__ void k_scanNB(const int* __restrict__ bcnt, int* __restrict__ bbase,
                         int* __restrict__ gcur, int NB) {
    __shared__ int s[1024];
    int tid = threadIdx.x;
    int v = (tid < NB) ? bcnt[tid] : 0;
    s[tid] = v;
    __syncthreads();
    for (int off = 1; off < 1024; off <<= 1) {
        int t = (tid >= off) ? s[tid - off] : 0;
        __syncthreads();
        s[tid] += t;
        __syncthreads();
    }
    if (tid < NB) {
        int e = s[tid] - v;
        bbase[tid] = e;
        gcur[tid] = e;
    }
}

// Per chunk: LDS hist -> block-exclusive scan -> one global atomic per
// (block,bucket) reserving contiguous runs -> LDS counting-sort of the
// chunk's packed pairs -> linear sweep writes pairs[] with adjacent lanes
// hitting adjacent addresses (full-line write-back, no partial sectors).
__global__ void k_binfill(const void* __restrict__ ei,
                          const int* __restrict__ flag, int E,
                          int* __restrict__ gcur, int* __restrict__ pairs,
                          int NB) {
    __shared__ int hist[1024];
    __shared__ int lbase[1024];
    __shared__ int lcur[1024];
    __shared__ int delta[1024];
    __shared__ int tsum[256];
    __shared__ unsigned sorted[CHUNK];
    __shared__ unsigned short sortedb[CHUNK];

    int tid = threadIdx.x;
    for (int i = tid; i < NB; i += 256) hist[i] = 0;
    __syncthreads();

    const bool is32 = (*flag != 0);
    long long base = (long long)blockIdx.x * CHUNK;
    int m = (int)min((long long)CHUNK, (long long)E - base);

    // phase 1: histogram of buckets
    for (int i = tid; i < m; i += 256) {
        int d = load_dst(ei, is32, E, base + i);
        atomicAdd(&hist[d >> SHIFT], 1);
    }
    __syncthreads();

    // phase 2: block-wide exclusive scan of hist[NB] (K entries per thread)
    int K = (NB + 255) >> 8;
    int s0 = tid * K;
    int local = 0;
    for (int j = 0; j < K; ++j) {
        int idx = s0 + j;
        if (idx < NB) local += hist[idx];
    }
    tsum[tid] = local;
    __syncthreads();
    for (int off = 1; off < 256; off <<= 1) {
        int t = (tid >= off) ? tsum[tid - off] : 0;
        __syncthreads();
        tsum[tid] += t;
        __syncthreads();
    }
    int run = tsum[tid] - local;
    for (int j = 0; j < K; ++j) {
        int idx = s0 + j;
        if (idx < NB) {
            lbase[idx] = run;
            lcur[idx] = run;
            run += hist[idx];
        }
    }
    __syncthreads();

    // phase 3: reserve global runs (one atomic per non-empty bucket)
    for (int i = tid; i < NB; i += 256) {
        int h = hist[i];
        if (h > 0) {
            int gpos = atomicAdd(&gcur[i], h);
            delta[i] = gpos - lbase[i];
        }
    }
    __syncthreads();

    // phase 4: counting-sort packed pairs into LDS
    for (int i = tid; i < m; i += 256) {
        int s = load_src(ei, is32, E, base + i);
        int d = load_dst(ei, is32, E, base + i);
        int bk = d >> SHIFT;
        int slot = atomicAdd(&lcur[bk], 1);
        sorted[slot] = ((unsigned)s << SHIFT) | (unsigned)(d & (NPB - 1));
        sortedb[slot] = (unsigned short)bk;
    }
    __syncthreads();

    // phase 5: coalesced writeout (dest is piecewise-linear in i)
    for (int i = tid; i < m; i += 256)
        pairs[i + delta[sortedb[i]]] = (int)sorted[i];
}

// One block per bucket: LDS histogram of its 128-node range -> dinv.
__global__ void k_deg_dinv(const int* __restrict__ pairs,
                           const int* __restrict__ bbase,
                           const int* __restrict__ bcnt,
                           float* __restrict__ dinv, int N) {
    __shared__ int deg[NPB];
    int tid = threadIdx.x;
    if (tid < NPB) deg[tid] = 0;
    __syncthreads();
    int b = blockIdx.x;
    int beg = bbase[b], c = bcnt[b];
    for (int i = tid; i < c; i += blockDim.x)
        atomicAdd(&deg[pairs[beg + i] & (NPB - 1)], 1);
    __syncthreads();
    if (tid < NPB) {
        int n = b * NPB + tid;
        if (n < N) dinv[n] = rsqrtf(1.0f + (float)deg[tid]);
    }
}

// y[n] = dinv[n] * (x[n] @ W), row padded to YPAD floats (64 B aligned)
__global__ void k_xw(const float* __restrict__ x, const float* __restrict__ W,
                     const float* __restrict__ dinv, float* __restrict__ y,
                     int N) {
    __shared__ float Wt[OUT_CH][IN_CH];
    for (int i = threadIdx.x; i < IN_CH * OUT_CH; i += blockDim.x) {
        int k = i / OUT_CH, c = i - k * OUT_CH;
        Wt[c][k] = W[i];
    }
    __syncthreads();

    int n = blockIdx.x * blockDim.x + threadIdx.x;
    if (n >= N) return;

    float acc[OUT_CH];
#pragma unroll
    for (int c = 0; c < OUT_CH; ++c) acc[c] = 0.0f;

    const float4* xr = (const float4*)(x + (size_t)n * IN_CH);
#pragma unroll 4
    for (int k4 = 0; k4 < IN_CH / 4; ++k4) {
        float4 xv = xr[k4];
#pragma unroll
        for (int c = 0; c < OUT_CH; ++c) {
            float4 wv = *(const float4*)&Wt[c][k4 * 4];
            acc[c] += xv.x * wv.x + xv.y * wv.y + xv.z * wv.z + xv.w * wv.w;
        }
    }

    float d = dinv[n];
    float4* yr = (float4*)(y + (size_t)n * YPAD);
    float4 o0, o1;
    o0.x = d * acc[0]; o0.y = d * acc[1]; o0.z = d * acc[2]; o0.w = d * acc[3];
    o1.x = d * acc[4]; o1.y = d * acc[5]; o1.z = d * acc[6]; o1.w = d * acc[7];
    yr[0] = o0;
    yr[1] = o1;
    float2 o2;
    o2.x = d * acc[8]; o2.y = d * acc[9];
    ((float2*)yr)[4] = o2;
}

// 4 blocks per bucket, block (b,s) owns slice s of bucket b's packed pairs.
// Per <=1024-pair round: counting-sort the pairs by dst row in LDS (int
// atomics only -- native ds ops), then thread t = (row<<1)|half privately
// accumulates its contiguous run of y[src] gathers in VGPRs. Halves combine
// via shfl; partial flushed coalesced. ZERO float LDS/global atomics.
__global__ void k_accum(const int* __restrict__ pairs,
                        const int* __restrict__ bbase,
                        const int* __restrict__ bcnt,
                        const float* __restrict__ y,
                        float* __restrict__ part) {
    __shared__ unsigned sorted[CCAP];
    __shared__ int hist[NPB];
    __shared__ int base[NPB];
    __shared__ int cur[NPB];

    int tid = threadIdx.x;
    int b = blockIdx.x >> 2;
    int s = blockIdx.x & 3;
    int beg = bbase[b];
    int c = bcnt[b];
    int lo = beg + (int)(((long long)c * s) >> 2);
    int hi = beg + (int)(((long long)c * (s + 1)) >> 2);

    int myrow = tid >> 1;
    int h = tid & 1;

    float acc[OUT_CH];
#pragma unroll
    for (int k = 0; k < OUT_CH; ++k) acc[k] = 0.0f;

    for (int clo = lo; clo < hi; clo += CCAP) {
        int m = min(CCAP, hi - clo);

        if (tid < NPB) hist[tid] = 0;
        __syncthreads();

        // read my <=4 pairs, build histogram (native int LDS atomics)
        unsigned mine[4];
        int nm = 0;
        for (int i = tid; i < m; i += 256) {
            unsigned pp = (unsigned)pairs[clo + i];
            mine[nm++] = pp;
            atomicAdd(&hist[pp & (NPB - 1)], 1);
        }
        __syncthreads();

        // exclusive scan of hist[128] (Hillis-Steele; all threads barrier)
        if (tid < NPB) base[tid] = hist[tid];
        __syncthreads();
        for (int off = 1; off < NPB; off <<= 1) {
            int t = 0;
            if (tid < NPB && tid >= off) t = base[tid - off];
            __syncthreads();
            if (tid < NPB) base[tid] += t;
            __syncthreads();
        }
        if (tid < NPB) {
            int e = base[tid] - hist[tid];
            base[tid] = e;
            cur[tid] = e;
        }
        __syncthreads();

        // scatter src ids into row-sorted order
        for (int j = 0; j < nm; ++j) {
            unsigned pp = mine[j];
            int slot = atomicAdd(&cur[pp & (NPB - 1)], 1);
            sorted[slot] = pp >> SHIFT;
        }
        __syncthreads();

        // private VGPR accumulation over my row's run (2 threads/row)
        int rb = base[myrow];
        int rl = hist[myrow];
        for (int j = h; j < rl; j += 2) {
            unsigned src = sorted[rb + j];
            const float4* yr = (const float4*)(y + (size_t)src * YPAD);
            float4 v0 = yr[0];
            float4 v1 = yr[1];
            float2 v2 = ((const float2*)yr)[4];
            acc[0] += v0.x; acc[1] += v0.y; acc[2] += v0.z; acc[3] += v0.w;
            acc[4] += v1.x; acc[5] += v1.y; acc[6] += v1.z; acc[7] += v1.w;
            acc[8] += v2.x; acc[9] += v2.y;
        }
        __syncthreads();  // protect hist/sorted before next round
    }

    // combine the two halves of each row (adjacent lanes)
#pragma unroll
    for (int k = 0; k < OUT_CH; ++k) acc[k] += __shfl_xor(acc[k], 1);

    if (h == 0) {
        float* dst = part + (size_t)blockIdx.x * (NPB * OUT_CH) +
                     (size_t)myrow * OUT_CH;
#pragma unroll
        for (int k = 0; k < OUT_CH; ++k) dst[k] = acc[k];
    }
}

// out[n][ch] = dinv[n] * (sum of 4 slice partials + y[n][ch]) + bias[ch]
__global__ void k_merge(const float* __restrict__ part,
                        const float* __restrict__ y,
                        const float* __restrict__ dinv,
                        const float* __restrict__ bias,
                        float* __restrict__ out, int N) {
    int idx = blockIdx.x * blockDim.x + threadIdx.x;
    if (idx >= N * OUT_CH) return;
    int n = idx / OUT_CH;
    int ch = idx - n * OUT_CH;
    int b = n >> SHIFT;
    int local = (n & (NPB - 1)) * OUT_CH + ch;
    size_t base_slot = (size_t)(b << 2);
    float s = part[(base_slot + 0) * (NPB * OUT_CH) + local] +
              part[(base_slot + 1) * (NPB * OUT_CH) + local] +
              part[(base_slot + 2) * (NPB * OUT_CH) + local] +
              part[(base_slot + 3) * (NPB * OUT_CH) + local];
    out[idx] = dinv[n] * (s + y[(size_t)n * YPAD + ch]) + bias[ch];
}

// ============================================================================
// Fallback path (atomic scatter) — used only if ws too small / N too large
// ============================================================================

__global__ void k_count_fb(const void* __restrict__ ei, int* __restrict__ cnt,
                           const int* __restrict__ flag, int E) {
    const bool is32 = (*flag != 0);
    long long i = (long long)blockIdx.x * blockDim.x + threadIdx.x;
    long long stride = (long long)gridDim.x * blockDim.x;
    for (; i < E; i += stride) atomicAdd(&cnt[load_dst(ei, is32, E, i)], 1);
}

__global__ void k_xw_fb(const float* __restrict__ x,
                        const float* __restrict__ W,
                        const int* __restrict__ cnt, float* __restrict__ dinv,
                        float* __restrict__ y, float* __restrict__ out_seed,
                        int N) {
    __shared__ float Wt[OUT_CH][IN_CH];
    for (int i = threadIdx.x; i < IN_CH * OUT_CH; i += blockDim.x) {
        int k = i / OUT_CH, c = i - k * OUT_CH;
        Wt[c][k] = W[i];
    }
    __syncthreads();
    int n = blockIdx.x * blockDim.x + threadIdx.x;
    if (n >= N) return;
    float acc[OUT_CH];
#pragma unroll
    for (int c = 0; c < OUT_CH; ++c) acc[c] = 0.0f;
    const float4* xr = (const float4*)(x + (size_t)n * IN_CH);
#pragma unroll 4
    for (int k4 = 0; k4 < IN_CH / 4; ++k4) {
        float4 xv = xr[k4];
#pragma unroll
        for (int c = 0; c < OUT_CH; ++c) {
            float4 wv = *(const float4*)&Wt[c][k4 * 4];
            acc[c] += xv.x * wv.x + xv.y * wv.y + xv.z * wv.z + xv.w * wv.w;
        }
    }
    float d = rsqrtf(1.0f + (float)cnt[n]);
    dinv[n] = d;
    float2* yr = (float2*)(y + (size_t)n * OUT_CH);
    float2* orow = (float2*)(out_seed + (size_t)n * OUT_CH);
#pragma unroll
    for (int c2 = 0; c2 < OUT_CH / 2; ++c2) {
        float2 v;
        v.x = d * acc[2 * c2];
        v.y = d * acc[2 * c2 + 1];
        yr[c2] = v;
        orow[c2] = v;
    }
}

__global__ void k_scatter_fb(const void* __restrict__ ei,
                             const float* __restrict__ y,
                             float* __restrict__ out,
                             const int* __restrict__ flag, int E) {
    const bool is32 = (*flag != 0);
    long long i = (long long)blockIdx.x * blockDim.x + threadIdx.x;
    long long stride = (long long)gridDim.x * blockDim.x;
    for (; i < E; i += stride) {
        long long s = load_src(ei, is32, E, i);
        long long t = load_dst(ei, is32, E, i);
        const float2* yr = (const float2*)(y + s * OUT_CH);
        float2 v0 = yr[0], v1 = yr[1], v2 = yr[2], v3 = yr[3], v4 = yr[4];
        float* orow = out + t * OUT_CH;
        atomicAdd(&orow[0], v0.x);
        atomicAdd(&orow[1], v0.y);
        atomicAdd(&orow[2], v1.x);
        atomicAdd(&orow[3], v1.y);
        atomicAdd(&orow[4], v2.x);
        atomicAdd(&orow[5], v2.y);
        atomicAdd(&orow[6], v3.x);
        atomicAdd(&orow[7], v3.y);
        atomicAdd(&orow[8], v4.x);
        atomicAdd(&orow[9], v4.y);
    }
}

__global__ void k_final_fb(const float* __restrict__ dinv,
                           const float* __restrict__ b,
                           float* __restrict__ out, int N) {
    int n = blockIdx.x * blockDim.x + threadIdx.x;
    if (n >= N) return;
    float d = dinv[n];
    float2* orow = (float2*)(out + (size_t)n * OUT_CH);
#pragma unroll
    for (int c2 = 0; c2 < OUT_CH / 2; ++c2) {
        float2 v = orow[c2];
        v.x = v.x * d + b[2 * c2];
        v.y = v.y * d + b[2 * c2 + 1];
        orow[c2] = v;
    }
}

// ============================================================================
// Launch
// ============================================================================

extern "C" void kernel_launch(void* const* d_in, const int* in_sizes, int n_in,
                              void* d_out, int out_size, void* d_ws,
                              size_t ws_size, hipStream_t stream) {
    const float* x = (const float*)d_in[0];
    const void* ei = d_in[1];
    const float* W = (const float*)d_in[2];
    const float* b = (const float*)d_in[3];
    float* out = (float*)d_out;

    int N = in_sizes[0] / IN_CH;  // 100000
    int E = in_sizes[1] / 2;      // 3200000

    int NB = (N + NPB - 1) / NPB;  // buckets (782)
    int nblkN = (N + 255) / 256;
    int nblkE = (E + CHUNK - 1) / CHUNK;

    // primary ws layout (4B units):
    //   bcnt[NB] | bbase[NB] | gcur[NB] | flag | pad16 | dinv[N] | pad16 |
    //   y[YPAD*N] (64B-aligned rows) | pairs[E] | pad16 | part[NB*4*1280]
    size_t off_dinv = (((size_t)3 * NB + 1) + 15) & ~(size_t)15;
    size_t off_y = ((off_dinv + (size_t)N) + 15) & ~(size_t)15;
    size_t off_pairs = off_y + (size_t)YPAD * N;
    size_t off_part = ((off_pairs + (size_t)E) + 15) & ~(size_t)15;
    size_t needed = (off_part + ((size_t)NB * 4) * (NPB * OUT_CH)) * 4;

    if (ws_size >= needed && NB <= 1024 && N <= (1 << 24)) {
        int* wsi = (int*)d_ws;
        int* bcnt = wsi;
        int* bbase = bcnt + NB;
        int* gcur = bbase + NB;
        int* flag = gcur + NB;
        float* dinv = (float*)(wsi + off_dinv);
        float* y = (float*)(wsi + off_y);
        int* pairs = wsi + off_pairs;
        float* part = (float*)(wsi + off_part);

        k_zero_i<<<(NB + 255) / 256, 256, 0, stream>>>(bcnt, NB);
        k_detect<<<1, 256, 0, stream>>>((const unsigned int*)ei, flag, 8192);
        k_bincount<<<nblkE, 256, 0, stream>>>(ei, flag, E, bcnt, NB);
        k_scanNB<<<1, 1024, 0, stream>>>(bcnt, bbase, gcur, NB);
        k_binfill<<<nblkE, 256, 0, stream>>>(ei, flag, E, gcur, pairs, NB);
        k_deg_dinv<<<NB, 256, 0, stream>>>(pairs, bbase, bcnt, dinv, N);
        k_xw<<<nblkN, 256, 0, stream>>>(x, W, dinv, y, N);
        k_accum<<<NB * 4, 256, 0, stream>>>(pairs, bbase, bcnt, y, part);
        int mthreads = N * OUT_CH;
        k_merge<<<(mthreads + 255) / 256, 256, 0, stream>>>(part, y, dinv, b,
                                                            out, N);
    } else {
        // -------- fallback: atomic scatter --------
        int* wsi = (int*)d_ws;
        int* cnt = wsi;                     // N
        int* flag = cnt + N;                // 1
        size_t off = ((size_t)N + 2) & ~(size_t)1;
        float* dinv = (float*)(wsi + off);  // N
        float* y = dinv + N;                // 10N

        k_zero_i<<<nblkN, 256, 0, stream>>>(cnt, N);
        k_detect<<<1, 256, 0, stream>>>((const unsigned int*)ei, flag, 8192);
        k_count_fb<<<4096, 256, 0, stream>>>(ei, cnt, flag, E);
        k_xw_fb<<<nblkN, 256, 0, stream>>>(x, W, cnt, dinv, y, out, N);
        k_scatter_fb<<<4096, 256, 0, stream>>>(ei, y, out, flag, E);
        k_final_fb<<<nblkN, 256, 0, stream>>>(dinv, b, out, N);
    }
}